// Round 7
// baseline (208.146 us; speedup 1.0000x reference)
//
#include <hip/hip_runtime.h>
#include <hip/hip_bf16.h>
#include <stdint.h>
#include <math.h>

typedef __attribute__((ext_vector_type(8))) __bf16 bf16x8;
typedef __attribute__((ext_vector_type(4))) __bf16 bf16x4;
typedef __attribute__((ext_vector_type(4))) float f32x4;
typedef __attribute__((ext_vector_type(4), aligned(4))) float f32x4u;
typedef __attribute__((ext_vector_type(2), aligned(4))) float f32x2u;

#define B_   2
#define M_   4096
#define QH_  16
#define D_   192
#define N_   255
#define VD_  128
#define NP_  256   // padded n

// ---- pre-pass 1: kb[b][h][n(256)][d(192)] bf16, row 255 zeroed ----
__global__ __launch_bounds__(256) void prep_k(const float* __restrict__ k,
                                              __bf16* __restrict__ kb) {
    const int t  = blockIdx.x * 256 + threadIdx.x;
    const int e0 = t * 8;
    const int row = e0 / D_;        // (b*QH+h)*256 + n
    const int d0  = e0 % D_;
    const int n   = row & 255;
    const int bh  = row >> 8;
    const int b   = bh >> 4, h = bh & 15;
    bf16x8 out;
    if (n < N_) {
        const float* src = k + ((size_t)((b * N_ + n) * QH_ + h)) * D_ + d0;
        f32x4 s0 = *(const f32x4*)src;
        f32x4 s1 = *(const f32x4*)(src + 4);
        out[0]=(__bf16)s0[0]; out[1]=(__bf16)s0[1]; out[2]=(__bf16)s0[2]; out[3]=(__bf16)s0[3];
        out[4]=(__bf16)s1[0]; out[5]=(__bf16)s1[1]; out[6]=(__bf16)s1[2]; out[7]=(__bf16)s1[3];
    } else {
        #pragma unroll
        for (int e = 0; e < 8; ++e) out[e] = (__bf16)0.f;
    }
    *(bf16x8*)(kb + (size_t)row * D_ + d0) = out;
}

// ---- pre-pass 2: vt[b][h][vd][n(256)] bf16 transposed, col 255 zeroed ----
__global__ __launch_bounds__(256) void prep_v(const float* __restrict__ v,
                                              __bf16* __restrict__ vt) {
    const int n  = threadIdx.x;          // 0..255
    const int r  = blockIdx.x;           // (b*QH+h)*128 + vd
    const int vd = r & 127;
    const int bh = r >> 7;
    const int b  = bh >> 4, h = bh & 15;
    float val = 0.f;
    if (n < N_) val = v[((size_t)((b * N_ + n) * QH_ + h)) * VD_ + vd];
    vt[(size_t)r * NP_ + n] = (__bf16)val;
}

// ---- main kernel: 1 wave/block, branch-free straight-line body ----
__global__ __launch_bounds__(64) void cattn_kernel(
    const float* __restrict__ q, const __bf16* __restrict__ kb,
    const __bf16* __restrict__ vt, float* __restrict__ o_out,
    float* __restrict__ p_out)
{
    const float scale = 0.07216878364870322f; // 192^-0.5
    const int bid  = blockIdx.x;
    const int iw16 = bid & 255;
    const int h    = (bid >> 8) & 15;
    const int b    = bid >> 12;
    const int bh   = b * QH_ + h;

    const int lane = threadIdx.x;   // 0..63
    const int g    = lane >> 4;     // 0..3
    const int c16  = lane & 15;
    const int iw   = iw16 << 4;
    const int i    = iw + c16;          // this lane's q row
    const bool dead = (i < 31);         // fully-masked row (o forced to 0)

    // ---- Q fragment (B-operand): b[e] = Q[i][s*32 + g*8 + e]
    bf16x8 bq[6];
    {
        const float* qrow = q + ((size_t)((b * M_ + i) * QH_ + h)) * D_;
        #pragma unroll
        for (int s = 0; s < 6; ++s) {
            f32x4 q0 = __builtin_nontemporal_load((const f32x4*)(qrow + s * 32 + g * 8));
            f32x4 q1 = __builtin_nontemporal_load((const f32x4*)(qrow + s * 32 + g * 8 + 4));
            bf16x8 a;
            a[0]=(__bf16)q0[0]; a[1]=(__bf16)q0[1]; a[2]=(__bf16)q0[2]; a[3]=(__bf16)q0[3];
            a[4]=(__bf16)q1[0]; a[5]=(__bf16)q1[1]; a[6]=(__bf16)q1[2]; a[7]=(__bf16)q1[3];
            bq[s] = a;
        }
    }

    // ---- S^T = K Q^T : all 16 tiles, straight-line (no per-tile branches)
    // lane (g,c16) holds S[i][n = jt*16 + g*4 + r]
    const __bf16* kbh = kb + (size_t)bh * NP_ * D_ + (size_t)c16 * D_ + g * 8;
    f32x4 sacc[16];
    #pragma unroll
    for (int jt = 0; jt < 16; ++jt) {
        f32x4 acc = {0.f, 0.f, 0.f, 0.f};
        const __bf16* krow = kbh + (size_t)jt * 16 * D_;   // A-row = jt*16 + c16
        #pragma unroll
        for (int s = 0; s < 6; ++s) {
            bf16x8 ka = *(const bf16x8*)(krow + s * 32);
            acc = __builtin_amdgcn_mfma_f32_16x16x32_bf16(ka, bq[s], acc, 0, 0, 0);
        }
        // causal-mask -> -1e30 ; nonexistent col 255 -> -inf.
        // Fully-masked rows then give m=-1e30, e=exp(0)=1 on 255 cols, sum=255
        // -> p = 1/255 uniform, exactly matching the reference. Col 255's -inf
        // exps to 0 in every case.
        #pragma unroll
        for (int r = 0; r < 4; ++r) {
            const int n = jt * 16 + g * 4 + r;
            const bool live = (n < N_) && (i >= 16 * n + 31);
            acc[r] = live ? acc[r] * scale : ((n < N_) ? -1e30f : -INFINITY);
        }
        sacc[jt] = acc;
    }

    // ---- softmax over this lane's row (reduce regs + xor 16/32)
    float m = -INFINITY;
    #pragma unroll
    for (int jt = 0; jt < 16; ++jt) {
        #pragma unroll
        for (int r = 0; r < 4; ++r) m = fmaxf(m, sacc[jt][r]);
    }
    m = fmaxf(m, __shfl_xor(m, 16));
    m = fmaxf(m, __shfl_xor(m, 32));
    float sum = 0.f;
    #pragma unroll
    for (int jt = 0; jt < 16; ++jt) {
        #pragma unroll
        for (int r = 0; r < 4; ++r) {
            float e = __expf(sacc[jt][r] - m);   // masked -> 0 ; dead-row -> 1
            sacc[jt][r] = e;
            sum += e;
        }
    }
    sum += __shfl_xor(sum, 16);
    sum += __shfl_xor(sum, 32);
    const float inv_l = 1.0f / sum;

    // ---- normalize, store p (vector, cached), pack bf16x4 -> u64 for shuffles
    unsigned long long pnp[16];
    float* prow = p_out + (size_t)(bh * M_ + i) * N_ + g * 4;
    #pragma unroll
    for (int jt = 0; jt < 16; ++jt) {
        f32x4 px;
        #pragma unroll
        for (int r = 0; r < 4; ++r) px[r] = sacc[jt][r] * inv_l;
        if (jt == 15 && g == 3) {
            // cols 252..254 only (col 255 doesn't exist)
            f32x2u p2; p2[0] = px[0]; p2[1] = px[1];
            *(f32x2u*)(prow + 15 * 16) = p2;
            prow[15 * 16 + 2] = px[2];
        } else {
            *(f32x4u*)(prow + jt * 16) = *(f32x4u*)&px;
        }
        union { bf16x4 v; unsigned long long u; } pk;
        #pragma unroll
        for (int r = 0; r < 4; ++r) pk.v[r] = (__bf16)px[r];
        pnp[jt] = pk.u;
    }

    // ---- O^T = V^T P^T : all 8 chunks, straight-line
    // lane (g,c16) holds O[i][vd = vdt*16 + g*4 + r]
    f32x4 oacc[8];
    #pragma unroll
    for (int t = 0; t < 8; ++t) oacc[t] = (f32x4){0.f, 0.f, 0.f, 0.f};

    const __bf16* vth = vt + (size_t)bh * VD_ * NP_ + (size_t)c16 * NP_ + g * 8;
    const int src0 = ((g & 1) << 5) + c16;   // lane (g_s=(g&1)*2, c16)
    const int src1 = src0 + 16;              // lane (g_s=(g&1)*2+1, c16)
    const bool selhi = (g >= 2);
    #pragma unroll
    for (int c = 0; c < 8; ++c) {
        unsigned long long lo0 = __shfl(pnp[2 * c],     src0);
        unsigned long long lo1 = __shfl(pnp[2 * c + 1], src0);
        unsigned long long hi0 = __shfl(pnp[2 * c],     src1);
        unsigned long long hi1 = __shfl(pnp[2 * c + 1], src1);
        union { struct { unsigned long long x, y; } u; bf16x8 v; } pa8;
        pa8.u.x = selhi ? lo1 : lo0;
        pa8.u.y = selhi ? hi1 : hi0;
        const bf16x8 pa = pa8.v;
        #pragma unroll
        for (int vdt = 0; vdt < 8; ++vdt) {
            bf16x8 vb = *(const bf16x8*)(vth + (size_t)vdt * 16 * NP_ + c * 32);
            oacc[vdt] = __builtin_amdgcn_mfma_f32_16x16x32_bf16(vb, pa, oacc[vdt], 0, 0, 0);
        }
    }

    // ---- write O (dwordx4 per lane; rows < 31 forced to zero)
    float* orow = o_out + ((size_t)(b * M_ + i) * QH_ + h) * VD_ + g * 4;
    #pragma unroll
    for (int vdt = 0; vdt < 8; ++vdt) {
        f32x4 ov;
        #pragma unroll
        for (int r = 0; r < 4; ++r) ov[r] = dead ? 0.f : oacc[vdt][r];
        *(f32x4*)(orow + vdt * 16) = ov;
    }
}

extern "C" void kernel_launch(void* const* d_in, const int* in_sizes, int n_in,
                              void* d_out, int out_size, void* d_ws, size_t ws_size,
                              hipStream_t stream) {
    (void)in_sizes; (void)n_in; (void)ws_size; (void)out_size;
    const float* q = (const float*)d_in[0];
    const float* k = (const float*)d_in[1];
    const float* v = (const float*)d_in[2];
    float* o_out = (float*)d_out;
    float* p_out = o_out + (size_t)B_ * M_ * QH_ * VD_;   // tuple: (o, p) flat

    __bf16* kb = (__bf16*)d_ws;
    __bf16* vt = kb + (size_t)B_ * QH_ * NP_ * D_;

    prep_k<<<dim3((B_ * QH_ * NP_ * D_ / 8 + 255) / 256), dim3(256), 0, stream>>>(k, kb);
    prep_v<<<dim3(B_ * QH_ * VD_), dim3(256), 0, stream>>>(v, vt);

    dim3 grid(B_ * QH_ * 256);   // 8192 one-wave blocks
    dim3 block(64);
    cattn_kernel<<<grid, block, 0, stream>>>(q, kb, vt, o_out, p_out);
}

// Round 9
// 184.186 us; speedup vs baseline: 1.1301x; 1.1301x over previous
//
#include <hip/hip_runtime.h>
#include <hip/hip_bf16.h>
#include <stdint.h>
#include <math.h>

typedef __attribute__((ext_vector_type(8))) __bf16 bf16x8;
typedef __attribute__((ext_vector_type(4))) __bf16 bf16x4;
typedef __attribute__((ext_vector_type(4))) float f32x4;
typedef __attribute__((ext_vector_type(4), aligned(4))) float f32x4u;
typedef __attribute__((ext_vector_type(2), aligned(4))) float f32x2u;

#define B_   2
#define M_   4096
#define QH_  16
#define D_   192
#define N_   255
#define VD_  128

// K image: per (bh,jt) tile, 6144 B laid out [s(6)][g(4)][c16(16)][16B]:
//   value = K[n = jt*16 + c16][d = s*32 + g*8 + e]   (n>=255 -> 0)
// V image: per (bh,c) chunk, 8192 B laid out [vdt(8)][g(4)][c16(16)][16B]:
//   value = V[n = c*32 + g*8 + e][vd = vdt*16 + c16] (n>=255 -> 0)
// Exactly the LDS byte order -> staging is lane-linear 16B chunks, and every
// ds_read_b128 instruction covers 1024 contiguous LDS bytes (conflict-free).

__global__ __launch_bounds__(256) void prep_k(const float* __restrict__ k,
                                              __bf16* __restrict__ kimg) {
    const int chunk = blockIdx.x * 256 + threadIdx.x;   // 196608 chunks
    const int wc   = chunk % 384;
    const int tile = chunk / 384;          // bh*16 + jt
    const int c16  = wc & 15;
    const int gq   = (wc >> 4) & 3;
    const int s    = wc >> 6;              // 0..5
    const int jt   = tile & 15;
    const int bh   = tile >> 4;
    const int b    = bh >> 4, h = bh & 15;
    const int n    = jt * 16 + c16;
    bf16x8 out;
    if (n < N_) {
        const float* src = k + ((size_t)((b * N_ + n) * QH_ + h)) * D_ + s * 32 + gq * 8;
        f32x4 s0 = *(const f32x4*)src;
        f32x4 s1 = *(const f32x4*)(src + 4);
        out[0]=(__bf16)s0[0]; out[1]=(__bf16)s0[1]; out[2]=(__bf16)s0[2]; out[3]=(__bf16)s0[3];
        out[4]=(__bf16)s1[0]; out[5]=(__bf16)s1[1]; out[6]=(__bf16)s1[2]; out[7]=(__bf16)s1[3];
    } else {
        #pragma unroll
        for (int e = 0; e < 8; ++e) out[e] = (__bf16)0.f;
    }
    *(bf16x8*)(kimg + (size_t)chunk * 8) = out;
}

__global__ __launch_bounds__(256) void prep_v(const float* __restrict__ v,
                                              __bf16* __restrict__ vimg) {
    const int chunk = blockIdx.x * 256 + threadIdx.x;   // 131072 chunks
    const int wc  = chunk & 511;
    const int img = chunk >> 9;            // bh*8 + c
    const int c16 = wc & 15;
    const int gq  = (wc >> 4) & 3;
    const int vdt = wc >> 6;               // 0..7
    const int c   = img & 7;
    const int bh  = img >> 3;
    const int b   = bh >> 4, h = bh & 15;
    const int vd  = vdt * 16 + c16;
    const int n0  = c * 32 + gq * 8;
    bf16x8 out;
    #pragma unroll
    for (int t = 0; t < 8; ++t) {
        const int n = n0 + t;
        float val = (n < N_) ? v[((size_t)((b * N_ + n) * QH_ + h)) * VD_ + vd] : 0.f;
        out[t] = (__bf16)val;
    }
    *(bf16x8*)(vimg + (size_t)chunk * 8) = out;
}

// ---- main kernel: 4 waves share K/V; reg-staged double-buffered LDS ----
__global__ __launch_bounds__(256) void cattn_kernel(
    const float* __restrict__ q, const __bf16* __restrict__ kimg,
    const __bf16* __restrict__ vimg, float* __restrict__ o_out,
    float* __restrict__ p_out)
{
    const float scale = 0.07216878364870322f; // 192^-0.5
    const int bid = blockIdx.x;     // bh in LOW 5 bits: consecutive bids ->
    const int bh  = bid & 31;       // different CUs, so each CU's blocks span
    const int ib  = bid >> 5;       // light..heavy q-tiles uniformly.
    const int h   = bh & 15;
    const int b   = bh >> 4;

    const int tid  = threadIdx.x;
    const int lane = tid & 63;
    const int wid  = tid >> 6;
    const int g    = lane >> 4;
    const int c16  = lane & 15;
    const int iw   = (ib << 6) + (wid << 4);
    const int i    = iw + c16;          // this lane's q row
    const bool dead = (i < 31);

    const int ntk = ((ib * 4 + 2) >> 4) + 1;   // block-uniform K-tile count, 1..16
    const int ncv = (ntk + 1) >> 1;            // V-chunk count, 1..8

    __shared__ __align__(16) __bf16 kls[2][3072];   // 2 x 6144 B
    __shared__ __align__(16) __bf16 vls[2][4096];   // 2 x 8192 B

    // staging offsets (bf16 units): wave w stages 16B chunks w and w+4
    const int so0 = wid * 512 + lane * 8;
    const int so1 = (wid + 4) * 512 + lane * 8;

    // ---- Q fragment (B-operand): bq[s][e] = Q[i][s*32 + g*8 + e]
    bf16x8 bq[6];
    {
        const float* qrow = q + ((size_t)((b * M_ + i) * QH_ + h)) * D_;
        #pragma unroll
        for (int s = 0; s < 6; ++s) {
            f32x4 q0 = __builtin_nontemporal_load((const f32x4*)(qrow + s * 32 + g * 8));
            f32x4 q1 = __builtin_nontemporal_load((const f32x4*)(qrow + s * 32 + g * 8 + 4));
            bf16x8 a;
            a[0]=(__bf16)q0[0]; a[1]=(__bf16)q0[1]; a[2]=(__bf16)q0[2]; a[3]=(__bf16)q0[3];
            a[4]=(__bf16)q1[0]; a[5]=(__bf16)q1[1]; a[6]=(__bf16)q1[2]; a[7]=(__bf16)q1[3];
            bq[s] = a;
        }
    }

    // ---- prologue: stage K tile 0 into kls[0] (K tile = 6 chunks of 1024 B)
    {
        const __bf16* ks = kimg + (size_t)(bh * 16) * 3072;
        uint4 a0 = *(const uint4*)(ks + so0);
        uint4 a1 = {0,0,0,0};
        if (wid < 2) a1 = *(const uint4*)(ks + so1);
        *(uint4*)(&kls[0][so0]) = a0;
        if (wid < 2) *(uint4*)(&kls[0][so1]) = a1;
    }

    f32x4 sacc[16];
    #pragma unroll
    for (int jt = 0; jt < 16; ++jt)
        sacc[jt] = (f32x4){-INFINITY, -INFINITY, -INFINITY, -INFINITY};

    // ---- K phases: barrier publishes prev stage; issue next loads; compute;
    //      ds_write late (VMEM wait lands after the MFMA block)
    #pragma unroll
    for (int jt = 0; jt < 16; ++jt) {
        if (jt >= ntk) break;              // block-uniform
        __syncthreads();
        uint4 a0, a1; bool two; __bf16* db;
        if (jt + 1 < ntk) {                // stage K tile jt+1
            const __bf16* ks = kimg + (size_t)(bh * 16 + jt + 1) * 3072;
            a0 = *(const uint4*)(ks + so0);
            two = (wid < 2);
            a1 = two ? *(const uint4*)(ks + so1) : (uint4){0,0,0,0};
            db = &kls[(jt + 1) & 1][0];
        } else {                           // last K phase: stage V chunk 0
            const __bf16* vs = vimg + (size_t)(bh * 8) * 4096;
            a0 = *(const uint4*)(vs + so0);
            a1 = *(const uint4*)(vs + so1);
            two = true;
            db = &vls[0][0];
        }
        // compute K tile jt from kls[jt&1]
        const __bf16* kbase = &kls[jt & 1][0] + g * 128 + c16 * 8;
        f32x4 acc = {0.f, 0.f, 0.f, 0.f};
        #pragma unroll
        for (int s = 0; s < 6; ++s) {
            bf16x8 ka = *(const bf16x8*)(kbase + s * 512);
            acc = __builtin_amdgcn_mfma_f32_16x16x32_bf16(ka, bq[s], acc, 0, 0, 0);
        }
        #pragma unroll
        for (int r = 0; r < 4; ++r) {
            const int n = jt * 16 + g * 4 + r;
            const bool live = (n < N_) && (i >= 16 * n + 31);
            acc[r] = live ? acc[r] * scale : ((n < N_) ? -1e30f : -INFINITY);
        }
        sacc[jt] = acc;
        // write-late
        *(uint4*)(db + so0) = a0;
        if (two) *(uint4*)(db + so1) = a1;
    }

    // ---- softmax over this lane's row (regs + xor 16/32); uncomputed -inf -> e=0
    float m = -INFINITY;
    #pragma unroll
    for (int jt = 0; jt < 16; ++jt) {
        #pragma unroll
        for (int r = 0; r < 4; ++r) m = fmaxf(m, sacc[jt][r]);
    }
    m = fmaxf(m, __shfl_xor(m, 16));
    m = fmaxf(m, __shfl_xor(m, 32));
    float sum = 0.f;
    #pragma unroll
    for (int jt = 0; jt < 16; ++jt) {
        #pragma unroll
        for (int r = 0; r < 4; ++r) {
            float e = __expf(sacc[jt][r] - m);
            sacc[jt][r] = e;
            sum += e;
        }
    }
    sum += __shfl_xor(sum, 16);
    sum += __shfl_xor(sum, 32);
    const float inv_l = 1.0f / sum;
    const float u255  = 0.00392156862745098f;  // dead rows: uniform 1/255

    // ---- normalize, store p, pack bf16x4 -> u64 for shuffles
    unsigned long long pnp[16];
    float* prow = p_out + (size_t)(bh * M_ + i) * N_ + g * 4;
    #pragma unroll
    for (int jt = 0; jt < 16; ++jt) {
        f32x4 px;
        #pragma unroll
        for (int r = 0; r < 4; ++r)
            px[r] = dead ? u255 : sacc[jt][r] * inv_l;
        if (jt == 15 && g == 3) {
            f32x2u p2; p2[0] = px[0]; p2[1] = px[1];     // cols 252..254 only
            *(f32x2u*)(prow + 15 * 16) = p2;
            prow[15 * 16 + 2] = px[2];
        } else {
            *(f32x4u*)(prow + jt * 16) = *(f32x4u*)&px;
        }
        union { bf16x4 v; unsigned long long u; } pk;
        #pragma unroll
        for (int r = 0; r < 4; ++r) pk.v[r] = (__bf16)px[r];
        pnp[jt] = pk.u;
    }

    // ---- V phases: O^T = V^T P^T ; lane (g,c16) holds O[i][vd = vdt*16+g*4+r]
    f32x4 oacc[8];
    #pragma unroll
    for (int t = 0; t < 8; ++t) oacc[t] = (f32x4){0.f, 0.f, 0.f, 0.f};

    const int src0 = ((g & 1) << 5) + c16;
    const int src1 = src0 + 16;
    const bool selhi = (g >= 2);
    #pragma unroll
    for (int c = 0; c < 8; ++c) {
        if (c >= ncv) break;               // block-uniform
        __syncthreads();
        uint4 a0, a1;
        const bool st = (c + 1 < ncv);
        __bf16* db = &vls[(c + 1) & 1][0];
        if (st) {                          // stage V chunk c+1 (8 chunks, 2/wave)
            const __bf16* vs = vimg + (size_t)(bh * 8 + c + 1) * 4096;
            a0 = *(const uint4*)(vs + so0);
            a1 = *(const uint4*)(vs + so1);
        }
        unsigned long long lo0 = __shfl(pnp[2 * c],     src0);
        unsigned long long lo1 = __shfl(pnp[2 * c + 1], src0);
        unsigned long long hi0 = __shfl(pnp[2 * c],     src1);
        unsigned long long hi1 = __shfl(pnp[2 * c + 1], src1);
        union { struct { unsigned long long x, y; } u; bf16x8 v; } pa8;
        pa8.u.x = selhi ? lo1 : lo0;
        pa8.u.y = selhi ? hi1 : hi0;
        const bf16x8 pa = pa8.v;
        const __bf16* vbase = &vls[c & 1][0] + g * 128 + c16 * 8;
        #pragma unroll
        for (int vdt = 0; vdt < 8; ++vdt) {
            bf16x8 vb = *(const bf16x8*)(vbase + vdt * 512);
            oacc[vdt] = __builtin_amdgcn_mfma_f32_16x16x32_bf16(vb, pa, oacc[vdt], 0, 0, 0);
        }
        if (st) {                          // write-late
            *(uint4*)(db + so0) = a0;
            *(uint4*)(db + so1) = a1;
        }
    }

    // ---- write O (rows < 31 forced to zero)
    float* orow = o_out + ((size_t)(b * M_ + i) * QH_ + h) * VD_ + g * 4;
    #pragma unroll
    for (int vdt = 0; vdt < 8; ++vdt) {
        f32x4 ov;
        #pragma unroll
        for (int r = 0; r < 4; ++r) ov[r] = dead ? 0.f : oacc[vdt][r];
        *(f32x4*)(orow + vdt * 16) = ov;
    }
}

extern "C" void kernel_launch(void* const* d_in, const int* in_sizes, int n_in,
                              void* d_out, int out_size, void* d_ws, size_t ws_size,
                              hipStream_t stream) {
    (void)in_sizes; (void)n_in; (void)ws_size; (void)out_size;
    const float* q = (const float*)d_in[0];
    const float* k = (const float*)d_in[1];
    const float* v = (const float*)d_in[2];
    float* o_out = (float*)d_out;
    float* p_out = o_out + (size_t)B_ * M_ * QH_ * VD_;   // tuple: (o, p) flat

    __bf16* kimg = (__bf16*)d_ws;                          // 32*16*3072*2B = 3.0 MB
    __bf16* vimg = kimg + (size_t)32 * 16 * 3072;          // 32*8*4096*2B  = 2.0 MB

    prep_k<<<dim3(768), dim3(256), 0, stream>>>(k, kimg);
    prep_v<<<dim3(512), dim3(256), 0, stream>>>(v, vimg);

    dim3 grid(64 * 32);   // bid = ib*32 + bh
    dim3 block(256);      // 4 waves, 64 q-rows per block
    cattn_kernel<<<grid, block, 0, stream>>>(q, kimg, vimg, o_out, p_out);
}

// Round 10
// 176.107 us; speedup vs baseline: 1.1819x; 1.0459x over previous
//
#include <hip/hip_runtime.h>
#include <hip/hip_bf16.h>
#include <stdint.h>
#include <math.h>

typedef __attribute__((ext_vector_type(8))) __bf16 bf16x8;
typedef __attribute__((ext_vector_type(4))) __bf16 bf16x4;
typedef __attribute__((ext_vector_type(4))) float f32x4;
typedef __attribute__((ext_vector_type(4), aligned(4))) float f32x4u;
typedef __attribute__((ext_vector_type(2), aligned(4))) float f32x2u;

#define B_   2
#define M_   4096
#define QH_  16
#define D_   192
#define N_   255
#define VD_  128

// K image: per (bh,jt) tile, 6144 B laid out [s(6)][g(4)][c16(16)][16B]:
//   value = K[n = jt*16 + c16][d = s*32 + g*8 + e]   (n>=255 -> 0)
// V image: per (bh,c) chunk, 8192 B laid out [vdt(8)][g(4)][c16(16)][16B]:
//   value = V[n = c*32 + g*8 + e][vd = vdt*16 + c16] (n>=255 -> 0)
// Exactly the LDS byte order -> staging is lane-linear 16B chunks, and every
// ds_read_b128 instruction covers 1024 contiguous LDS bytes (conflict-free).

__global__ __launch_bounds__(256) void prep_k(const float* __restrict__ k,
                                              __bf16* __restrict__ kimg) {
    const int chunk = blockIdx.x * 256 + threadIdx.x;   // 196608 chunks
    const int wc   = chunk % 384;
    const int tile = chunk / 384;          // bh*16 + jt
    const int c16  = wc & 15;
    const int gq   = (wc >> 4) & 3;
    const int s    = wc >> 6;              // 0..5
    const int jt   = tile & 15;
    const int bh   = tile >> 4;
    const int b    = bh >> 4, h = bh & 15;
    const int n    = jt * 16 + c16;
    bf16x8 out;
    if (n < N_) {
        const float* src = k + ((size_t)((b * N_ + n) * QH_ + h)) * D_ + s * 32 + gq * 8;
        f32x4 s0 = *(const f32x4*)src;
        f32x4 s1 = *(const f32x4*)(src + 4);
        out[0]=(__bf16)s0[0]; out[1]=(__bf16)s0[1]; out[2]=(__bf16)s0[2]; out[3]=(__bf16)s0[3];
        out[4]=(__bf16)s1[0]; out[5]=(__bf16)s1[1]; out[6]=(__bf16)s1[2]; out[7]=(__bf16)s1[3];
    } else {
        #pragma unroll
        for (int e = 0; e < 8; ++e) out[e] = (__bf16)0.f;
    }
    *(bf16x8*)(kimg + (size_t)chunk * 8) = out;
}

__global__ __launch_bounds__(256) void prep_v(const float* __restrict__ v,
                                              __bf16* __restrict__ vimg) {
    const int chunk = blockIdx.x * 256 + threadIdx.x;   // 131072 chunks
    const int wc  = chunk & 511;
    const int img = chunk >> 9;            // bh*8 + c
    const int c16 = wc & 15;
    const int gq  = (wc >> 4) & 3;
    const int vdt = wc >> 6;               // 0..7
    const int c   = img & 7;
    const int bh  = img >> 3;
    const int b   = bh >> 4, h = bh & 15;
    const int vd  = vdt * 16 + c16;
    const int n0  = c * 32 + gq * 8;
    bf16x8 out;
    #pragma unroll
    for (int t = 0; t < 8; ++t) {
        const int n = n0 + t;
        float val = (n < N_) ? v[((size_t)((b * N_ + n) * QH_ + h)) * VD_ + vd] : 0.f;
        out[t] = (__bf16)val;
    }
    *(bf16x8*)(vimg + (size_t)chunk * 8) = out;
}

// ---- main kernel: 4 waves share K/V; reg-staged double-buffered LDS ----
// __launch_bounds__(256, 2): min 2 waves/EU -> 256-VGPR budget. Peak live
// state is ~150 regs (sacc 64 + bq 24 + pnp 32 + staging + addr); without
// this the allocator targets ~7 waves/EU (72 regs) and spills ~20 KB/wave
// to scratch (R9: WRITE_SIZE 516 MB vs 198 ideal). LDS 28 KB caps at 5
// blocks/CU regardless, so the extra "occupancy" was unreachable anyway.
__global__ __launch_bounds__(256, 2) void cattn_kernel(
    const float* __restrict__ q, const __bf16* __restrict__ kimg,
    const __bf16* __restrict__ vimg, float* __restrict__ o_out,
    float* __restrict__ p_out)
{
    const float scale = 0.07216878364870322f; // 192^-0.5
    const int bid = blockIdx.x;     // bh in LOW 5 bits: consecutive bids ->
    const int bh  = bid & 31;       // different CUs, so each CU's blocks span
    const int ib  = bid >> 5;       // light..heavy q-tiles uniformly.
    const int h   = bh & 15;
    const int b   = bh >> 4;

    const int tid  = threadIdx.x;
    const int lane = tid & 63;
    const int wid  = tid >> 6;
    const int g    = lane >> 4;
    const int c16  = lane & 15;
    const int iw   = (ib << 6) + (wid << 4);
    const int i    = iw + c16;          // this lane's q row
    const bool dead = (i < 31);

    const int ntk = ((ib * 4 + 2) >> 4) + 1;   // block-uniform K-tile count, 1..16
    const int ncv = (ntk + 1) >> 1;            // V-chunk count, 1..8

    __shared__ __align__(16) __bf16 kls[2][3072];   // 2 x 6144 B
    __shared__ __align__(16) __bf16 vls[2][4096];   // 2 x 8192 B

    // staging offsets (bf16 units): wave w stages 16B chunks w and w+4
    const int so0 = wid * 512 + lane * 8;
    const int so1 = (wid + 4) * 512 + lane * 8;

    // ---- Q fragment (B-operand): bq[s][e] = Q[i][s*32 + g*8 + e]
    bf16x8 bq[6];
    {
        const float* qrow = q + ((size_t)((b * M_ + i) * QH_ + h)) * D_;
        #pragma unroll
        for (int s = 0; s < 6; ++s) {
            f32x4 q0 = __builtin_nontemporal_load((const f32x4*)(qrow + s * 32 + g * 8));
            f32x4 q1 = __builtin_nontemporal_load((const f32x4*)(qrow + s * 32 + g * 8 + 4));
            bf16x8 a;
            a[0]=(__bf16)q0[0]; a[1]=(__bf16)q0[1]; a[2]=(__bf16)q0[2]; a[3]=(__bf16)q0[3];
            a[4]=(__bf16)q1[0]; a[5]=(__bf16)q1[1]; a[6]=(__bf16)q1[2]; a[7]=(__bf16)q1[3];
            bq[s] = a;
        }
    }

    // ---- prologue: stage K tile 0 into kls[0] (K tile = 6 chunks of 1024 B)
    {
        const __bf16* ks = kimg + (size_t)(bh * 16) * 3072;
        uint4 a0 = *(const uint4*)(ks + so0);
        uint4 a1 = {0,0,0,0};
        if (wid < 2) a1 = *(const uint4*)(ks + so1);
        *(uint4*)(&kls[0][so0]) = a0;
        if (wid < 2) *(uint4*)(&kls[0][so1]) = a1;
    }

    f32x4 sacc[16];
    #pragma unroll
    for (int jt = 0; jt < 16; ++jt)
        sacc[jt] = (f32x4){-INFINITY, -INFINITY, -INFINITY, -INFINITY};

    // ---- K phases: barrier publishes prev stage; issue next loads; compute;
    //      ds_write late (VMEM wait lands after the MFMA block)
    #pragma unroll
    for (int jt = 0; jt < 16; ++jt) {
        if (jt >= ntk) break;              // block-uniform
        __syncthreads();
        uint4 a0, a1; bool two; __bf16* db;
        if (jt + 1 < ntk) {                // stage K tile jt+1
            const __bf16* ks = kimg + (size_t)(bh * 16 + jt + 1) * 3072;
            a0 = *(const uint4*)(ks + so0);
            two = (wid < 2);
            a1 = two ? *(const uint4*)(ks + so1) : (uint4){0,0,0,0};
            db = &kls[(jt + 1) & 1][0];
        } else {                           // last K phase: stage V chunk 0
            const __bf16* vs = vimg + (size_t)(bh * 8) * 4096;
            a0 = *(const uint4*)(vs + so0);
            a1 = *(const uint4*)(vs + so1);
            two = true;
            db = &vls[0][0];
        }
        // compute K tile jt from kls[jt&1]
        const __bf16* kbase = &kls[jt & 1][0] + g * 128 + c16 * 8;
        f32x4 acc = {0.f, 0.f, 0.f, 0.f};
        #pragma unroll
        for (int s = 0; s < 6; ++s) {
            bf16x8 ka = *(const bf16x8*)(kbase + s * 512);
            acc = __builtin_amdgcn_mfma_f32_16x16x32_bf16(ka, bq[s], acc, 0, 0, 0);
        }
        #pragma unroll
        for (int r = 0; r < 4; ++r) {
            const int n = jt * 16 + g * 4 + r;
            const bool live = (n < N_) && (i >= 16 * n + 31);
            acc[r] = live ? acc[r] * scale : ((n < N_) ? -1e30f : -INFINITY);
        }
        sacc[jt] = acc;
        // write-late
        *(uint4*)(db + so0) = a0;
        if (two) *(uint4*)(db + so1) = a1;
    }

    // ---- softmax over this lane's row (regs + xor 16/32); uncomputed -inf -> e=0
    float m = -INFINITY;
    #pragma unroll
    for (int jt = 0; jt < 16; ++jt) {
        #pragma unroll
        for (int r = 0; r < 4; ++r) m = fmaxf(m, sacc[jt][r]);
    }
    m = fmaxf(m, __shfl_xor(m, 16));
    m = fmaxf(m, __shfl_xor(m, 32));
    float sum = 0.f;
    #pragma unroll
    for (int jt = 0; jt < 16; ++jt) {
        #pragma unroll
        for (int r = 0; r < 4; ++r) {
            float e = __expf(sacc[jt][r] - m);
            sacc[jt][r] = e;
            sum += e;
        }
    }
    sum += __shfl_xor(sum, 16);
    sum += __shfl_xor(sum, 32);
    const float inv_l = 1.0f / sum;
    const float u255  = 0.00392156862745098f;  // dead rows: uniform 1/255

    // ---- normalize, store p, pack bf16x4 -> u64 for shuffles
    unsigned long long pnp[16];
    float* prow = p_out + (size_t)(bh * M_ + i) * N_ + g * 4;
    #pragma unroll
    for (int jt = 0; jt < 16; ++jt) {
        f32x4 px;
        #pragma unroll
        for (int r = 0; r < 4; ++r)
            px[r] = dead ? u255 : sacc[jt][r] * inv_l;
        if (jt == 15 && g == 3) {
            f32x2u p2; p2[0] = px[0]; p2[1] = px[1];     // cols 252..254 only
            *(f32x2u*)(prow + 15 * 16) = p2;
            prow[15 * 16 + 2] = px[2];
        } else {
            *(f32x4u*)(prow + jt * 16) = *(f32x4u*)&px;
        }
        union { bf16x4 v; unsigned long long u; } pk;
        #pragma unroll
        for (int r = 0; r < 4; ++r) pk.v[r] = (__bf16)px[r];
        pnp[jt] = pk.u;
    }

    // ---- V phases: O^T = V^T P^T ; lane (g,c16) holds O[i][vd = vdt*16+g*4+r]
    f32x4 oacc[8];
    #pragma unroll
    for (int t = 0; t < 8; ++t) oacc[t] = (f32x4){0.f, 0.f, 0.f, 0.f};

    const int src0 = ((g & 1) << 5) + c16;
    const int src1 = src0 + 16;
    const bool selhi = (g >= 2);
    #pragma unroll
    for (int c = 0; c < 8; ++c) {
        if (c >= ncv) break;               // block-uniform
        __syncthreads();
        uint4 a0, a1;
        const bool st = (c + 1 < ncv);
        __bf16* db = &vls[(c + 1) & 1][0];
        if (st) {                          // stage V chunk c+1 (8 chunks, 2/wave)
            const __bf16* vs = vimg + (size_t)(bh * 8 + c + 1) * 4096;
            a0 = *(const uint4*)(vs + so0);
            a1 = *(const uint4*)(vs + so1);
        }
        unsigned long long lo0 = __shfl(pnp[2 * c],     src0);
        unsigned long long lo1 = __shfl(pnp[2 * c + 1], src0);
        unsigned long long hi0 = __shfl(pnp[2 * c],     src1);
        unsigned long long hi1 = __shfl(pnp[2 * c + 1], src1);
        union { struct { unsigned long long x, y; } u; bf16x8 v; } pa8;
        pa8.u.x = selhi ? lo1 : lo0;
        pa8.u.y = selhi ? hi1 : hi0;
        const bf16x8 pa = pa8.v;
        const __bf16* vbase = &vls[c & 1][0] + g * 128 + c16 * 8;
        #pragma unroll
        for (int vdt = 0; vdt < 8; ++vdt) {
            bf16x8 vb = *(const bf16x8*)(vbase + vdt * 512);
            oacc[vdt] = __builtin_amdgcn_mfma_f32_16x16x32_bf16(vb, pa, oacc[vdt], 0, 0, 0);
        }
        if (st) {                          // write-late
            *(uint4*)(db + so0) = a0;
            *(uint4*)(db + so1) = a1;
        }
    }

    // ---- write O (rows < 31 forced to zero)
    float* orow = o_out + ((size_t)(b * M_ + i) * QH_ + h) * VD_ + g * 4;
    #pragma unroll
    for (int vdt = 0; vdt < 8; ++vdt) {
        f32x4 ov;
        #pragma unroll
        for (int r = 0; r < 4; ++r) ov[r] = dead ? 0.f : oacc[vdt][r];
        *(f32x4*)(orow + vdt * 16) = ov;
    }
}

extern "C" void kernel_launch(void* const* d_in, const int* in_sizes, int n_in,
                              void* d_out, int out_size, void* d_ws, size_t ws_size,
                              hipStream_t stream) {
    (void)in_sizes; (void)n_in; (void)ws_size; (void)out_size;
    const float* q = (const float*)d_in[0];
    const float* k = (const float*)d_in[1];
    const float* v = (const float*)d_in[2];
    float* o_out = (float*)d_out;
    float* p_out = o_out + (size_t)B_ * M_ * QH_ * VD_;   // tuple: (o, p) flat

    __bf16* kimg = (__bf16*)d_ws;                          // 32*16*3072*2B = 3.0 MB
    __bf16* vimg = kimg + (size_t)32 * 16 * 3072;          // 32*8*4096*2B  = 2.0 MB

    prep_k<<<dim3(768), dim3(256), 0, stream>>>(k, kimg);
    prep_v<<<dim3(512), dim3(256), 0, stream>>>(v, vimg);

    dim3 grid(64 * 32);   // bid = ib*32 + bh
    dim3 block(256);      // 4 waves, 64 q-rows per block
    cattn_kernel<<<grid, block, 0, stream>>>(q, kimg, vimg, o_out, p_out);
}